// Round 18
// baseline (44.642 us; speedup 1.0000x reference)
//
#include <hip/hip_runtime.h>

#define NPIX (512*512)
#define NIMG 32
#define CTR 255.5f
#define NCH 64            // chunks (blocks) per image
#define NTHR 256
#define NP1 17            // stats per chunk
#define PLANE (NIMG*NCH)  // 2048

typedef float v4f __attribute__((ext_vector_type(4)));

__device__ __forceinline__ double wredd(double v) {
#pragma unroll
    for (int off = 32; off; off >>= 1) v += __shfl_down(v, off, 64);
    return v;
}

__device__ __forceinline__ double aload(const double* p) {
    return __hip_atomic_load(p, __ATOMIC_RELAXED, __HIP_MEMORY_SCOPE_AGENT);
}
__device__ __forceinline__ void astore(double* p, double v) {
    __hip_atomic_store(p, v, __ATOMIC_RELAXED, __HIP_MEMORY_SCOPE_AGENT);
}

// Single fused kernel. One NT-load pass over x; 17 sums per (img,chunk)
// published via relaxed agent-scope atomic stores; last-arriving block per
// image (int counter, zeroed by a hipMemsetAsync graph node) finalizes on
// one wave. No fences, no spins, no fp64 atomics (R9/R10/R14 lessons).
//  0:Sg 1:Sg2 2:G10 3:G01 4:G20 5:G11 6:G02 7:G30 8:G21 9:G12 10:G03
//  11:S|g| 12:S|g|u 13:S|g|v 14:Ssgn 15:Ssgn*u 16:Ssgn*v   (coords - 255.5)
__global__ __launch_bounds__(NTHR) void k1(const float* __restrict__ x,
                                           double* __restrict__ p1,
                                           int* __restrict__ ctr,
                                           float* __restrict__ out) {
    int img = blockIdx.x >> 6;
    int chunk = blockIdx.x & (NCH - 1);
    size_t cb = (size_t)chunk * (NPIX / NCH);   // 4096 px per chunk
    const float* xr = x + (size_t)img * 3 * NPIX;

    v4f Rv[4], Gv[4], Bv[4];
#pragma unroll
    for (int j = 0; j < 4; ++j) {
        size_t off = cb + ((size_t)j * NTHR + threadIdx.x) * 4;
        Rv[j] = __builtin_nontemporal_load((const v4f*)(xr + off));
        Gv[j] = __builtin_nontemporal_load((const v4f*)(xr + NPIX + off));
        Bv[j] = __builtin_nontemporal_load((const v4f*)(xr + 2 * NPIX + off));
    }

    float A[NP1];
#pragma unroll
    for (int a = 0; a < NP1; ++a) A[a] = 0.0f;

#pragma unroll
    for (int j = 0; j < 4; ++j) {
        size_t off = cb + ((size_t)j * NTHR + threadIdx.x) * 4;
        float g0 = 0.299f * Rv[j].x + 0.587f * Gv[j].x + 0.114f * Bv[j].x;
        float g1 = 0.299f * Rv[j].y + 0.587f * Gv[j].y + 0.114f * Bv[j].y;
        float g2 = 0.299f * Rv[j].z + 0.587f * Gv[j].z + 0.114f * Bv[j].z;
        float g3 = 0.299f * Rv[j].w + 0.587f * Gv[j].w + 0.114f * Bv[j].w;

        float v = (float)(int)(off >> 9) - CTR;
        float u0 = (float)(int)(off & 511) - CTR;
        float v2 = v * v, v3 = v2 * v;

        // per-quad Q-moments of g over du=0..3
        float s23 = g2 + g3, s123 = g1 + s23;
        float Q0 = g0 + s123;
        float Q1 = s123 + s23 + g3;                 // g1+2g2+3g3
        float t = fmaf(2.0f, g3, s23);              // g2+3g3
        float Q2 = fmaf(2.0f, t, Q1);               // g1+4g2+9g3
        float w = fmaf(3.0f, g3, s23);              // g2+4g3
        float Q3 = fmaf(6.0f, w, Q1);               // g1+8g2+27g3

        // Q-moments of |g| and sign(g)
        float a0 = fabsf(g0), a1 = fabsf(g1), a2 = fabsf(g2), a3 = fabsf(g3);
        float as23 = a2 + a3, as123 = a1 + as23;
        float QA0 = a0 + as123;
        float QA1 = as123 + as23 + a3;
        float s0 = copysignf(1.0f, g0), s1 = copysignf(1.0f, g1);
        float s2 = copysignf(1.0f, g2), s3 = copysignf(1.0f, g3);
        float ss23 = s2 + s3, ss123 = s1 + ss23;
        float QS0 = s0 + ss123;
        float QS1 = ss123 + ss23 + s3;

        // binomial expansion about u0
        float u02 = u0 * u0, u03 = u02 * u0;
        float tu = u0 + u0, t3u = 3.0f * u0, t3u2 = 3.0f * u02;
        float m10 = fmaf(u0, Q0, Q1);
        float m20 = fmaf(tu, Q1, Q2);  m20 = fmaf(u02, Q0, m20);
        float m30 = fmaf(t3u, Q2, Q3); m30 = fmaf(t3u2, Q1, m30);
        m30 = fmaf(u03, Q0, m30);
        float ma10 = fmaf(u0, QA0, QA1);
        float ms10 = fmaf(u0, QS0, QS1);

        A[0] += Q0;
        A[1] = fmaf(g0, g0, A[1]); A[1] = fmaf(g1, g1, A[1]);
        A[1] = fmaf(g2, g2, A[1]); A[1] = fmaf(g3, g3, A[1]);
        A[2] += m10;
        A[3] = fmaf(v, Q0, A[3]);
        A[4] += m20;
        A[5] = fmaf(v, m10, A[5]);
        A[6] = fmaf(v2, Q0, A[6]);
        A[7] += m30;
        A[8] = fmaf(v, m20, A[8]);
        A[9] = fmaf(v2, m10, A[9]);
        A[10] = fmaf(v3, Q0, A[10]);
        A[11] += QA0;
        A[12] += ma10;
        A[13] = fmaf(v, QA0, A[13]);
        A[14] += QS0;
        A[15] += ms10;
        A[16] = fmaf(v, QS0, A[16]);
    }

    __shared__ double lds[4][NP1];
    int lane = threadIdx.x & 63, wv = threadIdx.x >> 6;
#pragma unroll
    for (int a = 0; a < NP1; ++a) {
        double s = wredd((double)A[a]);
        if (lane == 0) lds[wv][a] = s;
    }
    __syncthreads();
    if (threadIdx.x < NP1)
        astore(&p1[(size_t)threadIdx.x * PLANE + (size_t)img * NCH + chunk],
               lds[0][threadIdx.x] + lds[1][threadIdx.x] + lds[2][threadIdx.x] + lds[3][threadIdx.x]);
    __syncthreads();   // vmcnt(0): astores retired before counter bump

    __shared__ int is_last;
    if (threadIdx.x == 0)
        is_last = (atomicAdd(&ctr[img], 1) == NCH - 1);
    __syncthreads();
    if (!is_last || threadIdx.x >= 64) return;

    // ---- finalize: one wave of the last-arriving block for this image ----
    double M[NP1];
#pragma unroll
    for (int a = 0; a < NP1; ++a)
        M[a] = aload(&p1[(size_t)a * PLANE + (size_t)img * NCH + lane]);
#pragma unroll
    for (int a = 0; a < NP1; ++a) M[a] = wredd(M[a]);

    if (lane == 0) {
        const double N = (double)NPIX;
        double G00 = M[0], Sg2 = M[1];
        double G10 = M[2], G01 = M[3], G20 = M[4], G11 = M[5], G02 = M[6];
        double G30 = M[7], G21 = M[8], G12 = M[9], G03 = M[10];

        double mean2 = G00 / N;
        double var = Sg2 / N - mean2 * mean2;
        if (var < 0.0) var = 0.0;
        double inv_std = 1.0 / (sqrt(var) + 1e-8);

        // sign-decomposition reconstruction of the |g - mean| sums
        double A0 = M[11] - mean2 * M[14];
        double Ax = M[12] - mean2 * M[15];
        double Ay = M[13] - mean2 * M[16];

        double s_chk = A0 * inv_std;
        double dx, dy;  // cx-255.5, cy-255.5
        if (s_chk < 1e-8) { dx = 0.5; dy = 0.5; }
        else { dx = Ax / A0; dy = Ay / A0; }

        double S2 = 512.0 * (512.0 * 512.0 - 1.0) / 12.0;
        double P20 = S2 * 512.0, P02 = S2 * 512.0;

        double W00 = G00 - mean2 * N;
        double W10 = G10, W01 = G01;
        double W20 = G20 - mean2 * P20;
        double W11 = G11;
        double W02 = G02 - mean2 * P02;
        double W30 = G30, W21 = G21, W12 = G12, W03 = G03;

        double N00 = W00;
        double N10 = W10 - dx * W00;
        double N01 = W01 - dy * W00;
        double N20 = W20 - 2.0 * dx * W10 + dx * dx * W00;
        double N11 = W11 - dx * W01 - dy * W10 + dx * dy * W00;
        double N02 = W02 - 2.0 * dy * W01 + dy * dy * W00;
        double N30 = W30 - 3.0 * dx * W20 + 3.0 * dx * dx * W10 - dx * dx * dx * W00;
        double N21 = W21 - dy * W20 - 2.0 * dx * W11 + 2.0 * dx * dy * W10
                   + dx * dx * W01 - dx * dx * dy * W00;
        double N12 = W12 - dx * W02 - 2.0 * dy * W11 + 2.0 * dx * dy * W01
                   + dy * dy * W10 - dx * dy * dy * W00;
        double N03 = W03 - 3.0 * dy * W02 + 3.0 * dy * dy * W01 - dy * dy * dy * W00;

        double cx = (double)CTR + dx, cy = (double)CTR + dy;
        double mdx = fmax(cx, 511.0 - cx), mdy = fmax(cy, 511.0 - cy);
        double max_r = sqrt(mdx * mdx + mdy * mdy) + 1e-8;
        double imr = 1.0 / max_r;
        double im1 = inv_std * imr, im2 = im1 * imr, im3 = im2 * imr;
        double inv_denom = 1.0 / (max_r * max_r + 1e-8);

        double S0 = N00 * inv_std;
        double R2 = (N20 + N02) * im2;
        double C1 = N10 * im1, S1 = N01 * im1;
        double C2 = (N20 - N02) * im2, Sm2 = 2.0 * N11 * im2;
        double C3 = (N30 - 3.0 * N12) * im3, Sm3 = (3.0 * N21 - N03) * im3;
        double C31 = (N30 + N12) * im3, S31 = (N21 + N03) * im3;

        double f0 = fabs(S0) * inv_denom;
        double f1 = sqrt(C1 * C1 + S1 * S1) * inv_denom;
        double f3 = sqrt(C2 * C2 + Sm2 * Sm2) * inv_denom;
        double f4 = fabs(2.0 * R2 - S0) * inv_denom;
        double f6 = sqrt(C3 * C3 + Sm3 * Sm3) * inv_denom;
        double a31r = 3.0 * C31 - 2.0 * C1, a31i = 3.0 * S31 - 2.0 * S1;
        double f7 = sqrt(a31r * a31r + a31i * a31i) * inv_denom;

        float* o = out + (size_t)img * 20;
        o[0] = (float)f0;
        o[1] = (float)f1; o[2] = (float)f1;
        o[3] = (float)f3; o[4] = (float)f4; o[5] = (float)f3;
        o[6] = (float)f6; o[7] = (float)f7; o[8] = (float)f7; o[9] = (float)f6;
        for (int k = 10; k < 20; ++k) o[k] = 0.0f;
    }
}

extern "C" void kernel_launch(void* const* d_in, const int* in_sizes, int n_in,
                              void* d_out, int out_size, void* d_ws, size_t ws_size,
                              hipStream_t stream) {
    const float* x = (const float*)d_in[0];
    float* out = (float*)d_out;

    int* ctr = (int*)d_ws;                               // 32 ints
    double* p1 = (double*)((char*)d_ws + 256);           // 17*2048 doubles

    hipMemsetAsync(ctr, 0, NIMG * sizeof(int), stream);  // graph memset node
    k1<<<NIMG * NCH, NTHR, 0, stream>>>(x, p1, ctr, out);
}

// Round 20
// 41.609 us; speedup vs baseline: 1.0729x; 1.0729x over previous
//
#include <hip/hip_runtime.h>

#define NPIX (512*512)
#define NIMG 32
#define CTR 255.5f
#define NCH 64            // chunks (blocks) per image
#define NTHR 256
#define NP1 17            // stats per chunk
#define PLANE (NIMG*NCH)  // 2048

typedef float v4f __attribute__((ext_vector_type(4)));

__device__ __forceinline__ double wredd(double v) {
#pragma unroll
    for (int off = 32; off; off >>= 1) v += __shfl_down(v, off, 64);
    return v;
}

__device__ __forceinline__ double aload(const double* p) {
    return __hip_atomic_load(p, __ATOMIC_RELAXED, __HIP_MEMORY_SCOPE_AGENT);
}
__device__ __forceinline__ void astore(double* p, double v) {
    __hip_atomic_store(p, v, __ATOMIC_RELAXED, __HIP_MEMORY_SCOPE_AGENT);
}

// Single fused kernel, no initialization anywhere. Last-arriver election via
// atomicInc(ctr, 63): from ANY start >= 63 (0xAA poison qualifies), arrival 1
// wraps to 0 and the block reading old==62 is the TRUE 64th arrival; the
// counter self-parks at 63 after every call (replay-deterministic).
// R19's modulo trick failed because poison mod 64 shifted the election point.
//  0:Sg 1:Sg2 2:G10 3:G01 4:G20 5:G11 6:G02 7:G30 8:G21 9:G12 10:G03
//  11:S|g| 12:S|g|u 13:S|g|v 14:Ssgn 15:Ssgn*u 16:Ssgn*v   (coords - 255.5)
__global__ __launch_bounds__(NTHR) void k1(const float* __restrict__ x,
                                           double* __restrict__ p1,
                                           unsigned int* __restrict__ ctr,
                                           float* __restrict__ out) {
    int img = blockIdx.x >> 6;
    int chunk = blockIdx.x & (NCH - 1);
    size_t cb = (size_t)chunk * (NPIX / NCH);   // 4096 px per chunk
    const float* xr = x + (size_t)img * 3 * NPIX;

    v4f Rv[4], Gv[4], Bv[4];
#pragma unroll
    for (int j = 0; j < 4; ++j) {
        size_t off = cb + ((size_t)j * NTHR + threadIdx.x) * 4;
        Rv[j] = __builtin_nontemporal_load((const v4f*)(xr + off));
        Gv[j] = __builtin_nontemporal_load((const v4f*)(xr + NPIX + off));
        Bv[j] = __builtin_nontemporal_load((const v4f*)(xr + 2 * NPIX + off));
    }

    float A[NP1];
#pragma unroll
    for (int a = 0; a < NP1; ++a) A[a] = 0.0f;

#pragma unroll
    for (int j = 0; j < 4; ++j) {
        size_t off = cb + ((size_t)j * NTHR + threadIdx.x) * 4;
        float g0 = 0.299f * Rv[j].x + 0.587f * Gv[j].x + 0.114f * Bv[j].x;
        float g1 = 0.299f * Rv[j].y + 0.587f * Gv[j].y + 0.114f * Bv[j].y;
        float g2 = 0.299f * Rv[j].z + 0.587f * Gv[j].z + 0.114f * Bv[j].z;
        float g3 = 0.299f * Rv[j].w + 0.587f * Gv[j].w + 0.114f * Bv[j].w;

        float v = (float)(int)(off >> 9) - CTR;
        float u0 = (float)(int)(off & 511) - CTR;
        float v2 = v * v, v3 = v2 * v;

        // per-quad Q-moments of g over du=0..3
        float s23 = g2 + g3, s123 = g1 + s23;
        float Q0 = g0 + s123;
        float Q1 = s123 + s23 + g3;                 // g1+2g2+3g3
        float t = fmaf(2.0f, g3, s23);              // g2+3g3
        float Q2 = fmaf(2.0f, t, Q1);               // g1+4g2+9g3
        float w = fmaf(3.0f, g3, s23);              // g2+4g3
        float Q3 = fmaf(6.0f, w, Q1);               // g1+8g2+27g3

        // Q-moments of |g| and sign(g)
        float a0 = fabsf(g0), a1 = fabsf(g1), a2 = fabsf(g2), a3 = fabsf(g3);
        float as23 = a2 + a3, as123 = a1 + as23;
        float QA0 = a0 + as123;
        float QA1 = as123 + as23 + a3;
        float s0 = copysignf(1.0f, g0), s1 = copysignf(1.0f, g1);
        float s2 = copysignf(1.0f, g2), s3 = copysignf(1.0f, g3);
        float ss23 = s2 + s3, ss123 = s1 + ss23;
        float QS0 = s0 + ss123;
        float QS1 = ss123 + ss23 + s3;

        // binomial expansion about u0
        float u02 = u0 * u0, u03 = u02 * u0;
        float tu = u0 + u0, t3u = 3.0f * u0, t3u2 = 3.0f * u02;
        float m10 = fmaf(u0, Q0, Q1);
        float m20 = fmaf(tu, Q1, Q2);  m20 = fmaf(u02, Q0, m20);
        float m30 = fmaf(t3u, Q2, Q3); m30 = fmaf(t3u2, Q1, m30);
        m30 = fmaf(u03, Q0, m30);
        float ma10 = fmaf(u0, QA0, QA1);
        float ms10 = fmaf(u0, QS0, QS1);

        A[0] += Q0;
        A[1] = fmaf(g0, g0, A[1]); A[1] = fmaf(g1, g1, A[1]);
        A[1] = fmaf(g2, g2, A[1]); A[1] = fmaf(g3, g3, A[1]);
        A[2] += m10;
        A[3] = fmaf(v, Q0, A[3]);
        A[4] += m20;
        A[5] = fmaf(v, m10, A[5]);
        A[6] = fmaf(v2, Q0, A[6]);
        A[7] += m30;
        A[8] = fmaf(v, m20, A[8]);
        A[9] = fmaf(v2, m10, A[9]);
        A[10] = fmaf(v3, Q0, A[10]);
        A[11] += QA0;
        A[12] += ma10;
        A[13] = fmaf(v, QA0, A[13]);
        A[14] += QS0;
        A[15] += ms10;
        A[16] = fmaf(v, QS0, A[16]);
    }

    __shared__ double lds[4][NP1];
    int lane = threadIdx.x & 63, wv = threadIdx.x >> 6;
#pragma unroll
    for (int a = 0; a < NP1; ++a) {
        double s = wredd((double)A[a]);
        if (lane == 0) lds[wv][a] = s;
    }
    __syncthreads();
    if (threadIdx.x < NP1)
        astore(&p1[(size_t)threadIdx.x * PLANE + (size_t)img * NCH + chunk],
               lds[0][threadIdx.x] + lds[1][threadIdx.x] + lds[2][threadIdx.x] + lds[3][threadIdx.x]);
    __syncthreads();   // vmcnt(0): astores retired before counter bump

    __shared__ int is_last;
    if (threadIdx.x == 0)
        is_last = (atomicInc(&ctr[img], NCH - 1) == NCH - 2);
    __syncthreads();
    if (!is_last || threadIdx.x >= 64) return;

    // ---- finalize: one wave of the last-arriving block for this image ----
    double M[NP1];
#pragma unroll
    for (int a = 0; a < NP1; ++a)
        M[a] = aload(&p1[(size_t)a * PLANE + (size_t)img * NCH + lane]);
#pragma unroll
    for (int a = 0; a < NP1; ++a) M[a] = wredd(M[a]);

    if (lane == 0) {
        const double N = (double)NPIX;
        double G00 = M[0], Sg2 = M[1];
        double G10 = M[2], G01 = M[3], G20 = M[4], G11 = M[5], G02 = M[6];
        double G30 = M[7], G21 = M[8], G12 = M[9], G03 = M[10];

        double mean2 = G00 / N;
        double var = Sg2 / N - mean2 * mean2;
        if (var < 0.0) var = 0.0;
        double inv_std = 1.0 / (sqrt(var) + 1e-8);

        // sign-decomposition reconstruction of the |g - mean| sums
        double A0 = M[11] - mean2 * M[14];
        double Ax = M[12] - mean2 * M[15];
        double Ay = M[13] - mean2 * M[16];

        double s_chk = A0 * inv_std;
        double dx, dy;  // cx-255.5, cy-255.5
        if (s_chk < 1e-8) { dx = 0.5; dy = 0.5; }
        else { dx = Ax / A0; dy = Ay / A0; }

        double S2 = 512.0 * (512.0 * 512.0 - 1.0) / 12.0;
        double P20 = S2 * 512.0, P02 = S2 * 512.0;

        double W00 = G00 - mean2 * N;
        double W10 = G10, W01 = G01;
        double W20 = G20 - mean2 * P20;
        double W11 = G11;
        double W02 = G02 - mean2 * P02;
        double W30 = G30, W21 = G21, W12 = G12, W03 = G03;

        double N00 = W00;
        double N10 = W10 - dx * W00;
        double N01 = W01 - dy * W00;
        double N20 = W20 - 2.0 * dx * W10 + dx * dx * W00;
        double N11 = W11 - dx * W01 - dy * W10 + dx * dy * W00;
        double N02 = W02 - 2.0 * dy * W01 + dy * dy * W00;
        double N30 = W30 - 3.0 * dx * W20 + 3.0 * dx * dx * W10 - dx * dx * dx * W00;
        double N21 = W21 - dy * W20 - 2.0 * dx * W11 + 2.0 * dx * dy * W10
                   + dx * dx * W01 - dx * dx * dy * W00;
        double N12 = W12 - dx * W02 - 2.0 * dy * W11 + 2.0 * dx * dy * W01
                   + dy * dy * W10 - dx * dy * dy * W00;
        double N03 = W03 - 3.0 * dy * W02 + 3.0 * dy * dy * W01 - dy * dy * dy * W00;

        double cx = (double)CTR + dx, cy = (double)CTR + dy;
        double mdx = fmax(cx, 511.0 - cx), mdy = fmax(cy, 511.0 - cy);
        double max_r = sqrt(mdx * mdx + mdy * mdy) + 1e-8;
        double imr = 1.0 / max_r;
        double im1 = inv_std * imr, im2 = im1 * imr, im3 = im2 * imr;
        double inv_denom = 1.0 / (max_r * max_r + 1e-8);

        double S0 = N00 * inv_std;
        double R2 = (N20 + N02) * im2;
        double C1 = N10 * im1, S1 = N01 * im1;
        double C2 = (N20 - N02) * im2, Sm2 = 2.0 * N11 * im2;
        double C3 = (N30 - 3.0 * N12) * im3, Sm3 = (3.0 * N21 - N03) * im3;
        double C31 = (N30 + N12) * im3, S31 = (N21 + N03) * im3;

        double f0 = fabs(S0) * inv_denom;
        double f1 = sqrt(C1 * C1 + S1 * S1) * inv_denom;
        double f3 = sqrt(C2 * C2 + Sm2 * Sm2) * inv_denom;
        double f4 = fabs(2.0 * R2 - S0) * inv_denom;
        double f6 = sqrt(C3 * C3 + Sm3 * Sm3) * inv_denom;
        double a31r = 3.0 * C31 - 2.0 * C1, a31i = 3.0 * S31 - 2.0 * S1;
        double f7 = sqrt(a31r * a31r + a31i * a31i) * inv_denom;

        float* o = out + (size_t)img * 20;
        o[0] = (float)f0;
        o[1] = (float)f1; o[2] = (float)f1;
        o[3] = (float)f3; o[4] = (float)f4; o[5] = (float)f3;
        o[6] = (float)f6; o[7] = (float)f7; o[8] = (float)f7; o[9] = (float)f6;
        for (int k = 10; k < 20; ++k) o[k] = 0.0f;
    }
}

extern "C" void kernel_launch(void* const* d_in, const int* in_sizes, int n_in,
                              void* d_out, int out_size, void* d_ws, size_t ws_size,
                              hipStream_t stream) {
    const float* x = (const float*)d_in[0];
    float* out = (float*)d_out;

    unsigned int* ctr = (unsigned int*)d_ws;             // 32 uints, never initialized
    double* p1 = (double*)((char*)d_ws + 256);           // 17*2048 doubles

    k1<<<NIMG * NCH, NTHR, 0, stream>>>(x, p1, ctr, out);
}

// Round 21
// 31.496 us; speedup vs baseline: 1.4174x; 1.3211x over previous
//
#include <hip/hip_runtime.h>

#define NPIX (512*512)
#define NIMG 32
#define CTR 255.5f
#define NCH 64            // chunks (blocks) per image
#define NTHR 256
#define NP1 17            // stats per chunk
#define PLANE (NIMG*NCH)  // 2048

typedef float v4f __attribute__((ext_vector_type(4)));

__device__ __forceinline__ double wredd(double v) {
#pragma unroll
    for (int off = 32; off; off >>= 1) v += __shfl_down(v, off, 64);
    return v;
}

// Single data pass over x with NON-TEMPORAL loads (streaming, no cache
// allocate). 17 sums per (img, chunk), plane-major p1 for coalesced finalize:
//  0:Sg 1:Sg2 2:G10 3:G01 4:G20 5:G11 6:G02 7:G30 8:G21 9:G12 10:G03
//  11:S|g| 12:S|g|u 13:S|g|v 14:Ssgn 15:Ssgn*u 16:Ssgn*v   (coords - 255.5)
__global__ __launch_bounds__(NTHR) void k1(const float* __restrict__ x,
                                           double* __restrict__ p1) {
    int img = blockIdx.x >> 6;
    int chunk = blockIdx.x & (NCH - 1);
    size_t cb = (size_t)chunk * (NPIX / NCH);   // 4096 px per chunk
    const float* xr = x + (size_t)img * 3 * NPIX;

    v4f Rv[4], Gv[4], Bv[4];
#pragma unroll
    for (int j = 0; j < 4; ++j) {
        size_t off = cb + ((size_t)j * NTHR + threadIdx.x) * 4;
        Rv[j] = __builtin_nontemporal_load((const v4f*)(xr + off));
        Gv[j] = __builtin_nontemporal_load((const v4f*)(xr + NPIX + off));
        Bv[j] = __builtin_nontemporal_load((const v4f*)(xr + 2 * NPIX + off));
    }

    float A[NP1];
#pragma unroll
    for (int a = 0; a < NP1; ++a) A[a] = 0.0f;

#pragma unroll
    for (int j = 0; j < 4; ++j) {
        size_t off = cb + ((size_t)j * NTHR + threadIdx.x) * 4;
        float g0 = 0.299f * Rv[j].x + 0.587f * Gv[j].x + 0.114f * Bv[j].x;
        float g1 = 0.299f * Rv[j].y + 0.587f * Gv[j].y + 0.114f * Bv[j].y;
        float g2 = 0.299f * Rv[j].z + 0.587f * Gv[j].z + 0.114f * Bv[j].z;
        float g3 = 0.299f * Rv[j].w + 0.587f * Gv[j].w + 0.114f * Bv[j].w;

        float v = (float)(int)(off >> 9) - CTR;
        float u0 = (float)(int)(off & 511) - CTR;
        float v2 = v * v, v3 = v2 * v;

        // per-quad Q-moments of g over du=0..3
        float s23 = g2 + g3, s123 = g1 + s23;
        float Q0 = g0 + s123;
        float Q1 = s123 + s23 + g3;                 // g1+2g2+3g3
        float t = fmaf(2.0f, g3, s23);              // g2+3g3
        float Q2 = fmaf(2.0f, t, Q1);               // g1+4g2+9g3
        float w = fmaf(3.0f, g3, s23);              // g2+4g3
        float Q3 = fmaf(6.0f, w, Q1);               // g1+8g2+27g3

        // Q-moments of |g| and sign(g)
        float a0 = fabsf(g0), a1 = fabsf(g1), a2 = fabsf(g2), a3 = fabsf(g3);
        float as23 = a2 + a3, as123 = a1 + as23;
        float QA0 = a0 + as123;
        float QA1 = as123 + as23 + a3;
        float s0 = copysignf(1.0f, g0), s1 = copysignf(1.0f, g1);
        float s2 = copysignf(1.0f, g2), s3 = copysignf(1.0f, g3);
        float ss23 = s2 + s3, ss123 = s1 + ss23;
        float QS0 = s0 + ss123;
        float QS1 = ss123 + ss23 + s3;

        // binomial expansion about u0
        float u02 = u0 * u0, u03 = u02 * u0;
        float tu = u0 + u0, t3u = 3.0f * u0, t3u2 = 3.0f * u02;
        float m10 = fmaf(u0, Q0, Q1);
        float m20 = fmaf(tu, Q1, Q2);  m20 = fmaf(u02, Q0, m20);
        float m30 = fmaf(t3u, Q2, Q3); m30 = fmaf(t3u2, Q1, m30);
        m30 = fmaf(u03, Q0, m30);
        float ma10 = fmaf(u0, QA0, QA1);
        float ms10 = fmaf(u0, QS0, QS1);

        A[0] += Q0;
        A[1] = fmaf(g0, g0, A[1]); A[1] = fmaf(g1, g1, A[1]);
        A[1] = fmaf(g2, g2, A[1]); A[1] = fmaf(g3, g3, A[1]);
        A[2] += m10;
        A[3] = fmaf(v, Q0, A[3]);
        A[4] += m20;
        A[5] = fmaf(v, m10, A[5]);
        A[6] = fmaf(v2, Q0, A[6]);
        A[7] += m30;
        A[8] = fmaf(v, m20, A[8]);
        A[9] = fmaf(v2, m10, A[9]);
        A[10] = fmaf(v3, Q0, A[10]);
        A[11] += QA0;
        A[12] += ma10;
        A[13] = fmaf(v, QA0, A[13]);
        A[14] += QS0;
        A[15] += ms10;
        A[16] = fmaf(v, QS0, A[16]);
    }

    __shared__ double lds[4][NP1];
    int lane = threadIdx.x & 63, wv = threadIdx.x >> 6;
#pragma unroll
    for (int a = 0; a < NP1; ++a) {
        double s = wredd((double)A[a]);
        if (lane == 0) lds[wv][a] = s;
    }
    __syncthreads();
    if (threadIdx.x < NP1)
        p1[(size_t)threadIdx.x * PLANE + (size_t)img * NCH + chunk] =
            lds[0][threadIdx.x] + lds[1][threadIdx.x] + lds[2][threadIdx.x] + lds[3][threadIdx.x];
}

// Finalize: one wave per image; plane-major p1 -> coalesced 512B per stat.
__global__ __launch_bounds__(64) void k3f(const double* __restrict__ p1,
                                          float* __restrict__ out) {
    int img = blockIdx.x;
    int lane = threadIdx.x;
    double M[NP1];
#pragma unroll
    for (int a = 0; a < NP1; ++a)
        M[a] = p1[(size_t)a * PLANE + (size_t)img * NCH + lane];
#pragma unroll
    for (int a = 0; a < NP1; ++a) M[a] = wredd(M[a]);

    if (lane == 0) {
        const double N = (double)NPIX;
        double G00 = M[0], Sg2 = M[1];
        double G10 = M[2], G01 = M[3], G20 = M[4], G11 = M[5], G02 = M[6];
        double G30 = M[7], G21 = M[8], G12 = M[9], G03 = M[10];

        double mean2 = G00 / N;
        double var = Sg2 / N - mean2 * mean2;
        if (var < 0.0) var = 0.0;
        double inv_std = 1.0 / (sqrt(var) + 1e-8);

        // sign-decomposition reconstruction of the |g - mean| sums
        double A0 = M[11] - mean2 * M[14];
        double Ax = M[12] - mean2 * M[15];
        double Ay = M[13] - mean2 * M[16];

        double s_chk = A0 * inv_std;
        double dx, dy;  // cx-255.5, cy-255.5
        if (s_chk < 1e-8) { dx = 0.5; dy = 0.5; }
        else { dx = Ax / A0; dy = Ay / A0; }

        double S2 = 512.0 * (512.0 * 512.0 - 1.0) / 12.0;
        double P20 = S2 * 512.0, P02 = S2 * 512.0;

        double W00 = G00 - mean2 * N;
        double W10 = G10, W01 = G01;
        double W20 = G20 - mean2 * P20;
        double W11 = G11;
        double W02 = G02 - mean2 * P02;
        double W30 = G30, W21 = G21, W12 = G12, W03 = G03;

        double N00 = W00;
        double N10 = W10 - dx * W00;
        double N01 = W01 - dy * W00;
        double N20 = W20 - 2.0 * dx * W10 + dx * dx * W00;
        double N11 = W11 - dx * W01 - dy * W10 + dx * dy * W00;
        double N02 = W02 - 2.0 * dy * W01 + dy * dy * W00;
        double N30 = W30 - 3.0 * dx * W20 + 3.0 * dx * dx * W10 - dx * dx * dx * W00;
        double N21 = W21 - dy * W20 - 2.0 * dx * W11 + 2.0 * dx * dy * W10
                   + dx * dx * W01 - dx * dx * dy * W00;
        double N12 = W12 - dx * W02 - 2.0 * dy * W11 + 2.0 * dx * dy * W01
                   + dy * dy * W10 - dx * dy * dy * W00;
        double N03 = W03 - 3.0 * dy * W02 + 3.0 * dy * dy * W01 - dy * dy * dy * W00;

        double cx = (double)CTR + dx, cy = (double)CTR + dy;
        double mdx = fmax(cx, 511.0 - cx), mdy = fmax(cy, 511.0 - cy);
        double max_r = sqrt(mdx * mdx + mdy * mdy) + 1e-8;
        double imr = 1.0 / max_r;
        double im1 = inv_std * imr, im2 = im1 * imr, im3 = im2 * imr;
        double inv_denom = 1.0 / (max_r * max_r + 1e-8);

        double S0 = N00 * inv_std;
        double R2 = (N20 + N02) * im2;
        double C1 = N10 * im1, S1 = N01 * im1;
        double C2 = (N20 - N02) * im2, Sm2 = 2.0 * N11 * im2;
        double C3 = (N30 - 3.0 * N12) * im3, Sm3 = (3.0 * N21 - N03) * im3;
        double C31 = (N30 + N12) * im3, S31 = (N21 + N03) * im3;

        double f0 = fabs(S0) * inv_denom;
        double f1 = sqrt(C1 * C1 + S1 * S1) * inv_denom;
        double f3 = sqrt(C2 * C2 + Sm2 * Sm2) * inv_denom;
        double f4 = fabs(2.0 * R2 - S0) * inv_denom;
        double f6 = sqrt(C3 * C3 + Sm3 * Sm3) * inv_denom;
        double a31r = 3.0 * C31 - 2.0 * C1, a31i = 3.0 * S31 - 2.0 * S1;
        double f7 = sqrt(a31r * a31r + a31i * a31i) * inv_denom;

        float* o = out + (size_t)img * 20;
        o[0] = (float)f0;
        o[1] = (float)f1; o[2] = (float)f1;
        o[3] = (float)f3; o[4] = (float)f4; o[5] = (float)f3;
        o[6] = (float)f6; o[7] = (float)f7; o[8] = (float)f7; o[9] = (float)f6;
        for (int k = 10; k < 20; ++k) o[k] = 0.0f;
    }
}

extern "C" void kernel_launch(void* const* d_in, const int* in_sizes, int n_in,
                              void* d_out, int out_size, void* d_ws, size_t ws_size,
                              hipStream_t stream) {
    const float* x = (const float*)d_in[0];
    float* out = (float*)d_out;

    double* p1 = (double*)d_ws;   // 17 * 2048 doubles = 278 KB

    k1<<<NIMG * NCH, NTHR, 0, stream>>>(x, p1);
    k3f<<<NIMG, 64, 0, stream>>>(p1, out);
}